// Round 13
// baseline (1376.428 us; speedup 1.0000x reference)
//
#include <hip/hip_runtime.h>
#include <hip/hip_bf16.h>

#define HDIM 256
#define NEG_SLOPE 0.2f
#define NB 128          // blocks for hist/scatter
#define SLICES 8        // edge slices per dst in the big-degree aggregator

typedef __attribute__((ext_vector_type(8))) short bf16x8;
typedef __attribute__((ext_vector_type(4))) float f32x4;

__device__ inline ushort f2b(float x) { __hip_bfloat16 h = __float2bfloat16(x); return *(ushort*)&h; }
__device__ inline float b2f(ushort u) { uint x = ((uint)u) << 16; return __int_as_float((int)x); }
__device__ inline void f2sp(float x, ushort& hi, ushort& lo) {
  hi = f2b(x);
  lo = f2b(x - b2f(hi));
}
__device__ inline float sp2f(ushort h, ushort l) { return b2f(h) + b2f(l); }

static inline int cdiv(int a, int b) { return (a + b - 1) / b; }

// ---------------------------------------------------------------- utilities
__global__ void fillf_kernel(float* __restrict__ p, float v, int n) {
  int i = blockIdx.x * blockDim.x + threadIdx.x;
  if (i < n) p[i] = v;
}

// out[i] = b3[i&1]  (logits initialized with bias; MLP2 epilogue atomically accumulates)
__global__ void out_init_kernel(float* __restrict__ out, const float* __restrict__ b3, int n) {
  int i = blockIdx.x * blockDim.x + threadIdx.x;
  if (i < n) out[i] = b3[i & 1];
}

// elementwise fp32 -> split hi/lo (same layout)
__global__ void split_kernel(const float* __restrict__ in,
                             ushort* __restrict__ hi, ushort* __restrict__ lo, int n) {
  int i = blockIdx.x * 256 + threadIdx.x;
  if (i >= n) return;
  ushort h, l; f2sp(in[i], h, l);
  hi[i] = h; lo[i] = l;
}

// W[K][N] fp32 -> WT split [N][K]; i indexes OUTPUT (contiguous writes, no RFO)
__global__ void wsplit_kernel(const float* __restrict__ W,
                              ushort* __restrict__ Whi, ushort* __restrict__ Wlo,
                              int K, int N) {
  int i = blockIdx.x * 256 + threadIdx.x;
  if (i >= K * N) return;
  int n = i / K, k = i - n * K;
  ushort h, l; f2sp(W[(size_t)k * N + n], h, l);
  Whi[i] = h;
  Wlo[i] = l;
}

// ---------------------------------------------------------------- direct MFMA GEMM (no LDS staging)
// A split [M][K] / gathered / packed-uint; B split [N][K]; direct 16B fragment loads.
// Block = 16 rows x 256 cols, 4 waves (wave = 16 rows x 64 cols, acc 1x4).
// AMODE: 0 split A; 2 gathered split rows (MLP1); 3 packed uint A (hi|lo<<16, MLP2).
// OUTMODE: 1 packed-uint C (h1, full-line 4B stores);
//          3 bf16 Cb via per-wave LDS tile (coalesced 128B row stores) + fused row-dots;
//          4 dots only (no C);  5 fused relu+W3 head: atomicAdd partial logits into Cf.
// NDOT: 1 -> dot1_out[row]; 2 -> also dot2_out[row].
template <int AMODE, int OUTMODE, int ACT, int NDOT>
__global__ __launch_bounds__(256) void gemm_dn(
    const ushort* __restrict__ Ahi, const ushort* __restrict__ Alo,
    const ushort* __restrict__ xdhi, const ushort* __restrict__ xdlo,
    const ushort* __restrict__ xchi, const ushort* __restrict__ xclo,
    const int* __restrict__ g1, const int* __restrict__ g2, const int* __restrict__ g3,
    int row0,
    const ushort* __restrict__ Bhi, const ushort* __restrict__ Blo,
    const float* __restrict__ bias,
    const float* __restrict__ dota, const float* __restrict__ dotb,
    float* __restrict__ dot1_out, float* __restrict__ dot2_out,
    float* __restrict__ Cf, ushort* __restrict__ Cb, uint* __restrict__ Cp,
    int M, int N, int K) {
  const int lane = threadIdx.x & 63;
  const int w = threadIdx.x >> 6;
  const int l16 = lane & 15;
  const int quad = lane >> 4;

  const int NX = N >> 8;
  const int NY = (M + 15) >> 4;
  int L = blockIdx.x;
  int mb, nb;
  if (NX == 1) { mb = L; nb = 0; }
  else {
    int NYa = NY & ~7;
    int tsw = NX * NYa;
    if (L < tsw) {
      mb = (L / (NX * 8)) * 8 + (L & 7);
      nb = (L >> 3) % NX;
    } else {
      int t = L - tsw;
      int rem = NY - NYa;
      mb = NYa + t % rem;
      nb = t / rem;
    }
  }
  const int m0 = mb * 16;
  const int cb = nb * 256 + w * 64;

  const ushort* bhp[4];
  const ushort* blp[4];
#pragma unroll
  for (int tn = 0; tn < 4; ++tn) {
    int col = cb + tn * 16 + l16;
    bhp[tn] = Bhi + (size_t)col * K;
    blp[tn] = Blo + (size_t)col * K;
  }

  int r_ = m0 + l16;
  const int arow = (r_ < M) ? r_ : (M - 1);   // clamped loads; stores guarded

  f32x4 acc[4];
#pragma unroll
  for (int j = 0; j < 4; ++j) acc[j] = (f32x4){0.f, 0.f, 0.f, 0.f};

  for (int kc = 0; kc < K; kc += 256) {
    const ushort* ahp = nullptr;
    const ushort* alp = nullptr;
    const uint* app = nullptr;
    if (AMODE == 2) {
      int seg = kc >> 8;
      const int* g = (seg == 0) ? g1 : (seg == 1 ? g2 : g3);
      const ushort* thi = (seg == 2) ? xchi : xdhi;
      const ushort* tlo = (seg == 2) ? xclo : xdlo;
      int idx = g[row0 + arow];
      ahp = thi + (size_t)idx * HDIM;
      alp = tlo + (size_t)idx * HDIM;
    } else if (AMODE == 3) {
      app = (const uint*)Ahi + (size_t)arow * K + kc;
    } else {
      ahp = Ahi + (size_t)arow * K + kc;
      alp = Alo + (size_t)arow * K + kc;
    }
#pragma unroll
    for (int k0 = 0; k0 < 256; k0 += 32) {
      bf16x8 ah, al, bh[4], bl[4];
      if (AMODE == 3) {
        uint4 p0 = *(const uint4*)(app + k0 + quad * 8);
        uint4 p1 = *(const uint4*)(app + k0 + quad * 8 + 4);
        uint q[8] = {p0.x, p0.y, p0.z, p0.w, p1.x, p1.y, p1.z, p1.w};
        union { uint u[4]; bf16x8 v; } uh, ul;
#pragma unroll
        for (int i = 0; i < 4; ++i) {
          uh.u[i] = __builtin_amdgcn_perm(q[2 * i + 1], q[2 * i], 0x05040100u);
          ul.u[i] = __builtin_amdgcn_perm(q[2 * i + 1], q[2 * i], 0x07060302u);
        }
        ah = uh.v; al = ul.v;
      } else {
        ah = *(const bf16x8*)(ahp + k0 + quad * 8);
        al = *(const bf16x8*)(alp + k0 + quad * 8);
      }
#pragma unroll
      for (int tn = 0; tn < 4; ++tn) {
        bh[tn] = *(const bf16x8*)(bhp[tn] + kc + k0 + quad * 8);
        bl[tn] = *(const bf16x8*)(blp[tn] + kc + k0 + quad * 8);
      }
#pragma unroll
      for (int tn = 0; tn < 4; ++tn) {
        acc[tn] = __builtin_amdgcn_mfma_f32_16x16x32_bf16(ah, bh[tn], acc[tn], 0, 0, 0);
        acc[tn] = __builtin_amdgcn_mfma_f32_16x16x32_bf16(ah, bl[tn], acc[tn], 0, 0, 0);
        acc[tn] = __builtin_amdgcn_mfma_f32_16x16x32_bf16(al, bh[tn], acc[tn], 0, 0, 0);
      }
    }
  }

  // ---- epilogues. C/D layout: col = lane&15, row = quad*4 + reg
  if (OUTMODE == 3 || OUTMODE == 4) {
    __shared__ float reds[4][16];
    __shared__ float redd[4][16];
    __shared__ ushort hbtile[4][16][68];   // pitch 68: 8B-aligned rows, conflict-free
    float d1[4] = {0.f, 0.f, 0.f, 0.f};
    float d2[4] = {0.f, 0.f, 0.f, 0.f};
#pragma unroll
    for (int tn = 0; tn < 4; ++tn) {
      int col = cb + tn * 16 + l16;
      float a1 = dota[col];
      float a2 = (NDOT == 2) ? dotb[col] : 0.f;
#pragma unroll
      for (int r = 0; r < 4; ++r) {
        float v = acc[tn][r];
        d1[r] += v * a1;
        if (NDOT == 2) d2[r] += v * a2;
        if (OUTMODE == 3) hbtile[w][quad * 4 + r][tn * 16 + l16] = f2b(v);
      }
    }
#pragma unroll
    for (int o = 1; o < 16; o <<= 1) {
#pragma unroll
      for (int r = 0; r < 4; ++r) {
        d1[r] += __shfl_xor(d1[r], o);
        if (NDOT == 2) d2[r] += __shfl_xor(d2[r], o);
      }
    }
    if (l16 == 0) {
#pragma unroll
      for (int r = 0; r < 4; ++r) {
        reds[w][quad * 4 + r] = d1[r];
        if (NDOT == 2) redd[w][quad * 4 + r] = d2[r];
      }
    }
    __syncthreads();
    if (threadIdx.x < 16) {
      int row = m0 + threadIdx.x;
      if (row < M) {
        dot1_out[row] = reds[0][threadIdx.x] + reds[1][threadIdx.x] +
                        reds[2][threadIdx.x] + reds[3][threadIdx.x];
        if (NDOT == 2)
          dot2_out[row] = redd[0][threadIdx.x] + redd[1][threadIdx.x] +
                          redd[2][threadIdx.x] + redd[3][threadIdx.x];
      }
    }
    if (OUTMODE == 3) {
      // coalesced Hb store: per instr, 4 rows x 128B contiguous
#pragma unroll
      for (int i2 = 0; i2 < 4; ++i2) {
        int fi = i2 * 64 + lane;
        int trow = fi >> 4;
        int tc = (fi & 15) * 4;
        int grow = m0 + trow;
        if (grow < M) {
          ushort4 val = *(const ushort4*)&hbtile[w][trow][tc];
          *(ushort4*)(Cb + (size_t)grow * N + cb + tc) = val;
        }
      }
    }
  } else if (OUTMODE == 1) {
#pragma unroll
    for (int tn = 0; tn < 4; ++tn) {
      int col = cb + tn * 16 + l16;
      float bv = bias[col];
#pragma unroll
      for (int r = 0; r < 4; ++r) {
        int row = m0 + quad * 4 + r;
        if (row >= M) continue;
        float v = acc[tn][r] + bv;
        if (ACT == 1) v = fmaxf(v, 0.f);
        ushort h, l; f2sp(v, h, l);
        Cp[(size_t)row * N + col] = (uint)h | ((uint)l << 16);
      }
    }
  } else {  // OUTMODE 5: fused relu + W3 dot -> atomic logits
    __shared__ float r5a[4][16];
    __shared__ float r5b[4][16];
    float d1[4] = {0.f, 0.f, 0.f, 0.f};
    float d2[4] = {0.f, 0.f, 0.f, 0.f};
#pragma unroll
    for (int tn = 0; tn < 4; ++tn) {
      int col = cb + tn * 16 + l16;
      float bv = bias[col];
      float w3a = dota[col * 2];
      float w3b = dota[col * 2 + 1];
#pragma unroll
      for (int r = 0; r < 4; ++r) {
        float v = fmaxf(acc[tn][r] + bv, 0.f);
        d1[r] += v * w3a;
        d2[r] += v * w3b;
      }
    }
#pragma unroll
    for (int o = 1; o < 16; o <<= 1) {
#pragma unroll
      for (int r = 0; r < 4; ++r) {
        d1[r] += __shfl_xor(d1[r], o);
        d2[r] += __shfl_xor(d2[r], o);
      }
    }
    if (l16 == 0) {
#pragma unroll
      for (int r = 0; r < 4; ++r) {
        r5a[w][quad * 4 + r] = d1[r];
        r5b[w][quad * 4 + r] = d2[r];
      }
    }
    __syncthreads();
    if (threadIdx.x < 16) {
      int row = m0 + threadIdx.x;
      if (row < M) {
        float sa = r5a[0][threadIdx.x] + r5a[1][threadIdx.x] + r5a[2][threadIdx.x] + r5a[3][threadIdx.x];
        float sb = r5b[0][threadIdx.x] + r5b[1][threadIdx.x] + r5b[2][threadIdx.x] + r5b[3][threadIdx.x];
        atomicAdd(&Cf[(size_t)row * 2 + 0], sa);
        atomicAdd(&Cf[(size_t)row * 2 + 1], sb);
      }
    }
  }
}

// ---------------------------------------------------------------- counting sort by dst
__global__ __launch_bounds__(256) void hist_kernel(
    const int* __restrict__ src, const int* __restrict__ dst, int E, int nloops,
    int Nd, int* __restrict__ offs) {
  extern __shared__ int bins[];
  int tot = E + nloops;
  int chunk = (tot + NB - 1) / NB;
  int b = blockIdx.x;
  int s0 = b * chunk, s1 = min(s0 + chunk, tot);
  for (int i = threadIdx.x; i < Nd; i += 256) bins[i] = 0;
  __syncthreads();
  for (int i = s0 + threadIdx.x; i < s1; i += 256) {
    int d = (i < E) ? dst[i] : (i - E);
    atomicAdd(&bins[d], 1);
  }
  __syncthreads();
  for (int i = threadIdx.x; i < Nd; i += 256) offs[(size_t)i * NB + b] = bins[i];
}

__global__ __launch_bounds__(256) void scan_bins_kernel(
    int* __restrict__ offs, int* __restrict__ binsum, int Nd) {
  int d = blockIdx.x * 4 + (threadIdx.x >> 6);
  if (d >= Nd) return;
  int lane = threadIdx.x & 63;
  int* p = offs + (size_t)d * NB;
  int v0 = p[2 * lane], v1 = p[2 * lane + 1];
  int s = v0 + v1;
  int t = s;
#pragma unroll
  for (int o = 1; o < 64; o <<= 1) { int u = __shfl_up(t, o); if (lane >= o) t += u; }
  int excl = t - s;
  p[2 * lane] = excl;
  p[2 * lane + 1] = excl + v0;
  if (lane == 63) binsum[d] = t;
}

__global__ __launch_bounds__(256) void scan_base_kernel(
    const int* __restrict__ binsum, int* __restrict__ rowptr, int Nd) {
  __shared__ int wsum[4];
  __shared__ int carry;
  if (threadIdx.x == 0) carry = 0;
  __syncthreads();
  int lane = threadIdx.x & 63, w = threadIdx.x >> 6;
  for (int t0 = 0; t0 < Nd; t0 += 256) {
    int i = t0 + threadIdx.x;
    int v = (i < Nd) ? binsum[i] : 0;
    int t = v;
#pragma unroll
    for (int o = 1; o < 64; o <<= 1) { int u = __shfl_up(t, o); if (lane >= o) t += u; }
    if (lane == 63) wsum[w] = t;
    __syncthreads();
    int add = carry;
    for (int k = 0; k < w; ++k) add += wsum[k];
    if (i < Nd) rowptr[i] = t - v + add;
    __syncthreads();
    if (threadIdx.x == 0) carry += wsum[0] + wsum[1] + wsum[2] + wsum[3];
    __syncthreads();
  }
  if (threadIdx.x == 0) rowptr[Nd] = carry;
}

__global__ __launch_bounds__(256) void scatter_kernel(
    const int* __restrict__ src, const int* __restrict__ dst, int E, int nloops,
    int Nd, const int* __restrict__ offs, const int* __restrict__ rowptr,
    uint* __restrict__ sd) {
  extern __shared__ int bins[];
  int tot = E + nloops;
  int chunk = (tot + NB - 1) / NB;
  int b = blockIdx.x;
  int s0 = b * chunk, s1 = min(s0 + chunk, tot);
  for (int i = threadIdx.x; i < Nd; i += 256) bins[i] = 0;
  __syncthreads();
  for (int i = s0 + threadIdx.x; i < s1; i += 256) {
    int s_, d_;
    if (i < E) { s_ = src[i]; d_ = dst[i]; }
    else       { s_ = d_ = i - E; }
    int local = atomicAdd(&bins[d_], 1);
    int pos = rowptr[d_] + offs[(size_t)d_ * NB + b] + local;
    sd[pos] = (uint)s_ | ((uint)d_ << 16);
  }
}

// ---------------------------------------------------------------- fused GAT edge phase
template <int ACT>
__global__ __launch_bounds__(256) void gat_agg_small(
    const int* __restrict__ rowptr, const uint* __restrict__ sd,
    const float* __restrict__ als, const float* __restrict__ ald,
    const ushort* __restrict__ Hb, const float* __restrict__ bias,
    ushort* __restrict__ Ohi, ushort* __restrict__ Olo, int n) {
  int d = blockIdx.x * 4 + (threadIdx.x >> 6);
  if (d >= n) return;
  int lane = threadIdx.x & 63;
  int r0 = rowptr[d], r1 = rowptr[d + 1];
  float aldd = ald[d];
  float dsum = 0.f;
  for (int j = r0 + lane; j < r1; j += 64) {
    float e = als[sd[j] & 0xffff] + aldd;
    e = (e > 0.f) ? e : NEG_SLOPE * e;
    dsum += __expf(e);
  }
#pragma unroll
  for (int o = 32; o; o >>= 1) dsum += __shfl_xor(dsum, o);
  float rden = 1.f / (dsum + 1e-16f);

  float4 acc = make_float4(0.f, 0.f, 0.f, 0.f);
  for (int b = r0; b < r1; b += 64) {
    int j = b + lane;
    float exv = 0.f; int srcv = 0;
    if (j < r1) {
      uint p = sd[j];
      srcv = p & 0xffff;
      float e = als[srcv] + aldd;
      e = (e > 0.f) ? e : NEG_SLOPE * e;
      exv = __expf(e) * rden;
    }
    int cnt = min(64, r1 - b);
    for (int t0 = 0; t0 < cnt; t0 += 8) {
      float cf[8]; int sv[8];
#pragma unroll
      for (int u = 0; u < 8; ++u) {
        cf[u] = __shfl(exv, t0 + u);
        sv[u] = __shfl(srcv, t0 + u);
      }
      ushort4 hv[8];
#pragma unroll
      for (int u = 0; u < 8; ++u)
        hv[u] = *(const ushort4*)(Hb + (size_t)sv[u] * HDIM + lane * 4);
#pragma unroll
      for (int u = 0; u < 8; ++u) {
        acc.x += cf[u] * b2f(hv[u].x);
        acc.y += cf[u] * b2f(hv[u].y);
        acc.z += cf[u] * b2f(hv[u].z);
        acc.w += cf[u] * b2f(hv[u].w);
      }
    }
  }
  int c = lane * 4;
  float v0 = acc.x + bias[c], v1 = acc.y + bias[c + 1];
  float v2 = acc.z + bias[c + 2], v3 = acc.w + bias[c + 3];
  if (ACT == 1) {
    v0 = fmaxf(v0, 0.f); v1 = fmaxf(v1, 0.f);
    v2 = fmaxf(v2, 0.f); v3 = fmaxf(v3, 0.f);
  } else {
    float ss = v0 * v0 + v1 * v1 + v2 * v2 + v3 * v3;
#pragma unroll
    for (int o = 32; o; o >>= 1) ss += __shfl_xor(ss, o);
    float sc = 1.0f / fmaxf(sqrtf(ss), 1e-12f);
    v0 *= sc; v1 *= sc; v2 *= sc; v3 *= sc;
  }
  ushort h0, l0, h1, l1, h2, l2, h3, l3;
  f2sp(v0, h0, l0); f2sp(v1, h1, l1); f2sp(v2, h2, l2); f2sp(v3, h3, l3);
  *(ushort4*)(Ohi + (size_t)d * HDIM + c) = (ushort4){h0, h1, h2, h3};
  *(ushort4*)(Olo + (size_t)d * HDIM + c) = (ushort4){l0, l1, l2, l3};
}

__global__ __launch_bounds__(256) void gat_agg_slice(
    const int* __restrict__ rowptr, const uint* __restrict__ sd,
    const float* __restrict__ als, const float* __restrict__ ald,
    const ushort* __restrict__ Hb, float* __restrict__ out32, int n) {
  int d = blockIdx.x / SLICES;
  int sl = blockIdx.x - d * SLICES;
  if (d >= n) return;
  int lane = threadIdx.x & 63, w = threadIdx.x >> 6;
  int r0 = rowptr[d], r1 = rowptr[d + 1];
  float aldd = ald[d];
  float dsum = 0.f;
  for (int j = r0 + threadIdx.x; j < r1; j += 256) {
    float e = als[sd[j] & 0xffff] + aldd;
    e = (e > 0.f) ? e : NEG_SLOPE * e;
    dsum += __expf(e);
  }
#pragma unroll
  for (int o = 32; o; o >>= 1) dsum += __shfl_xor(dsum, o);
  __shared__ float wd[4];
  if (lane == 0) wd[w] = dsum;
  __syncthreads();
  float rden = 1.f / (wd[0] + wd[1] + wd[2] + wd[3] + 1e-16f);
  int deg = r1 - r0;
  int per_b = (deg + SLICES - 1) / SLICES;
  int b0 = r0 + sl * per_b, b1 = min(b0 + per_b, r1);
  int wdeg = b1 - b0;
  if (wdeg <= 0) return;
  int per_w = (wdeg + 3) >> 2;
  int w0 = b0 + w * per_w, w1 = min(w0 + per_w, b1);

  float4 acc = make_float4(0.f, 0.f, 0.f, 0.f);
  for (int b = w0; b < w1; b += 64) {
    int j = b + lane;
    float exv = 0.f; int srcv = 0;
    if (j < w1) {
      uint p = sd[j];
      srcv = p & 0xffff;
      float e = als[srcv] + aldd;
      e = (e > 0.f) ? e : NEG_SLOPE * e;
      exv = __expf(e) * rden;
    }
    int cnt = min(64, w1 - b);
    for (int t0 = 0; t0 < cnt; t0 += 8) {
      float cf[8]; int sv[8];
#pragma unroll
      for (int u = 0; u < 8; ++u) {
        cf[u] = __shfl(exv, t0 + u);
        sv[u] = __shfl(srcv, t0 + u);
      }
      ushort4 hv[8];
#pragma unroll
      for (int u = 0; u < 8; ++u)
        hv[u] = *(const ushort4*)(Hb + (size_t)sv[u] * HDIM + lane * 4);
#pragma unroll
      for (int u = 0; u < 8; ++u) {
        acc.x += cf[u] * b2f(hv[u].x);
        acc.y += cf[u] * b2f(hv[u].y);
        acc.z += cf[u] * b2f(hv[u].z);
        acc.w += cf[u] * b2f(hv[u].w);
      }
    }
  }
  float* o = out32 + (size_t)d * HDIM + lane * 4;
  atomicAdd(o + 0, acc.x); atomicAdd(o + 1, acc.y);
  atomicAdd(o + 2, acc.z); atomicAdd(o + 3, acc.w);
}

__global__ void finish_relu_sp(const float* __restrict__ acc, const float* __restrict__ bias,
                               ushort* __restrict__ ohi, ushort* __restrict__ olo, int total) {
  int i = blockIdx.x * blockDim.x + threadIdx.x;
  if (i >= total) return;
  int c = i & (HDIM - 1);
  float v = fmaxf(acc[i] + bias[c], 0.f);
  ushort h, l; f2sp(v, h, l);
  ohi[i] = h; olo[i] = l;
}

// ---------------------------------------------------------------- head
__global__ __launch_bounds__(256) void l2norm_sp_kernel(
    const ushort* __restrict__ ihi, const ushort* __restrict__ ilo,
    ushort* __restrict__ ohi, ushort* __restrict__ olo, int n) {
  int row = blockIdx.x * 4 + (threadIdx.x >> 6);
  if (row >= n) return;
  int lane = threadIdx.x & 63;
  float v[4];
  float ss = 0.f;
#pragma unroll
  for (int u = 0; u < 4; ++u) {
    int c = lane + u * 64;
    float t = sp2f(ihi[(size_t)row * HDIM + c], ilo[(size_t)row * HDIM + c]);
    v[u] = t;
    ss += t * t;
  }
#pragma unroll
  for (int off = 32; off; off >>= 1) ss += __shfl_xor(ss, off);
  float sc = 1.0f / fmaxf(sqrtf(ss), 1e-12f);
#pragma unroll
  for (int u = 0; u < 4; ++u) {
    int c = lane + u * 64;
    ushort h, l; f2sp(v[u] * sc, h, l);
    ohi[(size_t)row * HDIM + c] = h;
    olo[(size_t)row * HDIM + c] = l;
  }
}

// ---------------------------------------------------------------- host side
static void build_sorted(hipStream_t stream,
                         const int* src, const int* dst, int E, int nloops, int Nd,
                         int* offs, int* binsum, int* rowptr, uint* sd) {
  size_t lds = (size_t)Nd * sizeof(int);
  hist_kernel<<<NB, 256, lds, stream>>>(src, dst, E, nloops, Nd, offs);
  scan_bins_kernel<<<cdiv(Nd, 4), 256, 0, stream>>>(offs, binsum, Nd);
  scan_base_kernel<<<1, 256, 0, stream>>>(binsum, rowptr, Nd);
  scatter_kernel<<<NB, 256, lds, stream>>>(src, dst, E, nloops, Nd, offs, rowptr, sd);
}

struct GatBufs {
  float *als, *ald, *out32;
  ushort* Hb;
};

static inline int gemm_grid(int M, int N) { return (N >> 8) * cdiv(M, 16); }

static void run_gat(hipStream_t stream,
                    const ushort* Xs_hi, const ushort* Xs_lo, int Ns,
                    const ushort* Xd_hi, const ushort* Xd_lo, int Nd, bool same,
                    const ushort* WThi, const ushort* WTlo,
                    const float* asrc, const float* adst, const float* bias,
                    const uint* sd, const int* rowptr,
                    const GatBufs& b, ushort* out_hi, ushort* out_lo, int act) {
  if (same) {
    gemm_dn<0, 3, 0, 2><<<gemm_grid(Ns, HDIM), 256, 0, stream>>>(
        Xs_hi, Xs_lo, nullptr, nullptr, nullptr, nullptr, nullptr, nullptr, nullptr, 0,
        WThi, WTlo, nullptr, asrc, adst, b.als, b.ald,
        nullptr, b.Hb, nullptr, Ns, HDIM, HDIM);
  } else {
    gemm_dn<0, 3, 0, 1><<<gemm_grid(Ns, HDIM), 256, 0, stream>>>(
        Xs_hi, Xs_lo, nullptr, nullptr, nullptr, nullptr, nullptr, nullptr, nullptr, 0,
        WThi, WTlo, nullptr, asrc, nullptr, b.als, nullptr,
        nullptr, b.Hb, nullptr, Ns, HDIM, HDIM);
    gemm_dn<0, 4, 0, 1><<<gemm_grid(Nd, HDIM), 256, 0, stream>>>(
        Xd_hi, Xd_lo, nullptr, nullptr, nullptr, nullptr, nullptr, nullptr, nullptr, 0,
        WThi, WTlo, nullptr, adst, nullptr, b.ald, nullptr,
        nullptr, nullptr, nullptr, Nd, HDIM, HDIM);
  }
  if (Nd <= 256) {
    fillf_kernel<<<cdiv(Nd * HDIM, 256), 256, 0, stream>>>(b.out32, 0.f, Nd * HDIM);
    gat_agg_slice<<<Nd * SLICES, 256, 0, stream>>>(rowptr, sd, b.als, b.ald, b.Hb, b.out32, Nd);
    finish_relu_sp<<<cdiv(Nd * HDIM, 256), 256, 0, stream>>>(b.out32, bias, out_hi, out_lo, Nd * HDIM);
  } else if (act == 0) {
    gat_agg_small<0><<<cdiv(Nd, 4), 256, 0, stream>>>(rowptr, sd, b.als, b.ald, b.Hb, bias, out_hi, out_lo, Nd);
  } else {
    gat_agg_small<1><<<cdiv(Nd, 4), 256, 0, stream>>>(rowptr, sd, b.als, b.ald, b.Hb, bias, out_hi, out_lo, Nd);
  }
}

extern "C" void kernel_launch(void* const* d_in, const int* in_sizes, int n_in,
                              void* d_out, int out_size, void* d_ws, size_t ws_size,
                              hipStream_t stream) {
  const float* drug_emb = (const float*)d_in[0];
  const float* prot_emb = (const float*)d_in[1];
  const float* cell_emb = (const float*)d_in[2];
  const float* W_pp = (const float*)d_in[3];
  const float* as_pp = (const float*)d_in[4];
  const float* ad_pp = (const float*)d_in[5];
  const float* b_pp = (const float*)d_in[6];
  const float* W_dp = (const float*)d_in[7];
  const float* as_dp = (const float*)d_in[8];
  const float* ad_dp = (const float*)d_in[9];
  const float* b_dp = (const float*)d_in[10];
  const float* W_cp = (const float*)d_in[11];
  const float* as_cp = (const float*)d_in[12];
  const float* ad_cp = (const float*)d_in[13];
  const float* b_cp = (const float*)d_in[14];
  const float* W1 = (const float*)d_in[15];
  const float* b1 = (const float*)d_in[16];
  const float* W2 = (const float*)d_in[17];
  const float* b2 = (const float*)d_in[18];
  const float* W3 = (const float*)d_in[19];
  const float* b3 = (const float*)d_in[20];
  const int* edge_pp = (const int*)d_in[21];
  const int* edge_dp = (const int*)d_in[22];
  const int* edge_cp = (const int*)d_in[23];
  const int* drug1 = (const int*)d_in[24];
  const int* drug2 = (const int*)d_in[25];
  const int* cellb = (const int*)d_in[26];

  const int ND = in_sizes[0] / HDIM;   // 2000
  const int NP = in_sizes[1] / HDIM;   // 19000
  const int NC = in_sizes[2] / HDIM;   // 100
  const int L = in_sizes[3] / (HDIM * HDIM);  // 2
  const int E_pp = in_sizes[21] / 2;
  const int E_dp = in_sizes[22] / 2;
  const int E_cp = in_sizes[23] / 2;
  const int B = in_sizes[24];          // 8192

  const int* src_pp = edge_pp;          const int* dst_pp = edge_pp + E_pp;
  const int* src_dp = edge_dp;          const int* dst_dp = edge_dp + E_dp;
  const int* src_cp = edge_cp;          const int* dst_cp = edge_cp + E_cp;
  const int tot_pp = E_pp + NP, tot_dp = E_dp, tot_cp = E_cp;

  // ---------------- workspace
  float* ws = (float*)d_ws;
  size_t off = 0;
  auto alloc = [&](size_t n) { float* p = ws + off; off += (n + 3) & ~(size_t)3; return p; };
  auto alloc_sp = [&](size_t n, ushort*& hi, ushort*& lo) {
    float* p = alloc(n); hi = (ushort*)p; lo = hi + n;
  };
  int maxN = NP > ND ? NP : ND; if (NC > maxN) maxN = NC;

  ushort *xp_hi, *xp_lo, *xd_hi, *xd_lo, *xc_hi, *xc_lo;
  ushort *xdn_hi, *xdn_lo, *xcn_hi, *xcn_lo;
  alloc_sp((size_t)NP * HDIM, xp_hi, xp_lo);
  alloc_sp((size_t)ND * HDIM, xd_hi, xd_lo);
  alloc_sp((size_t)NC * HDIM, xc_hi, xc_lo);
  alloc_sp((size_t)ND * HDIM, xdn_hi, xdn_lo);
  alloc_sp((size_t)NC * HDIM, xcn_hi, xcn_lo);
  ushort *WTpp_hi, *WTpp_lo, *WTdp_hi, *WTdp_lo, *WTcp_hi, *WTcp_lo;
  alloc_sp((size_t)L * HDIM * HDIM, WTpp_hi, WTpp_lo);
  alloc_sp((size_t)L * HDIM * HDIM, WTdp_hi, WTdp_lo);
  alloc_sp((size_t)L * HDIM * HDIM, WTcp_hi, WTcp_lo);
  int* binsum = (int*)alloc(maxN);
  int* rp_pp = (int*)alloc(NP + 1);
  int* rp_dp = (int*)alloc(ND + 1);
  int* rp_cp = (int*)alloc(NC + 1);
  uint* sd_pp = (uint*)alloc(tot_pp);
  uint* sd_dp = (uint*)alloc(tot_dp);
  uint* sd_cp = (uint*)alloc(tot_cp);
  float* out32 = alloc((size_t)NC * HDIM);

  // scratch region S: {Hb, als, ald} <-> offs (sort) <-> MLP bufs
  size_t S0 = off;
  ushort* Hb = (ushort*)(ws + S0);                         // NP*HDIM ushorts (9.7 MB)
  float* als = (float*)(Hb + (size_t)NP * HDIM);
  float* ald = als + maxN;
  // MLP overlay (after graph phase)
  ushort* W1T_hi = (ushort*)(ws + S0);                     // 768*1536 each
  ushort* W1T_lo = W1T_hi + (size_t)768 * 1536;
  ushort* W2T_hi = W1T_lo + (size_t)768 * 1536;            // 1536*512 each
  ushort* W2T_lo = W2T_hi + (size_t)1536 * 512;
  const int CH = 4096;
  uint* h1p = (uint*)(W2T_lo + (size_t)1536 * 512);        // CH*1536 packed uints (25 MB)
  (void)ws_size; (void)n_in; (void)out_size;

  // ---- sort builds (offs overlays S; dead before Hb first written)
  int* offs = (int*)(ws + S0);
  build_sorted(stream, src_pp, dst_pp, E_pp, NP, NP, offs, binsum, rp_pp, sd_pp);
  build_sorted(stream, src_dp, dst_dp, E_dp, 0, ND, offs, binsum, rp_dp, sd_dp);
  build_sorted(stream, src_cp, dst_cp, E_cp, 0, NC, offs, binsum, rp_cp, sd_cp);

  // ---- embeddings -> split hi/lo into x* (layer-0 inputs)
  split_kernel<<<cdiv(NP * HDIM, 256), 256, 0, stream>>>(prot_emb, xp_hi, xp_lo, NP * HDIM);
  split_kernel<<<cdiv(ND * HDIM, 256), 256, 0, stream>>>(drug_emb, xd_hi, xd_lo, ND * HDIM);
  split_kernel<<<cdiv(NC * HDIM, 256), 256, 0, stream>>>(cell_emb, xc_hi, xc_lo, NC * HDIM);

  // ---- graph weight splits (transposed [N][K])
  for (int l = 0; l < L; ++l) {
    int WOFF = l * HDIM * HDIM;
    wsplit_kernel<<<cdiv(HDIM * HDIM, 256), 256, 0, stream>>>(W_pp + WOFF, WTpp_hi + WOFF, WTpp_lo + WOFF, HDIM, HDIM);
    wsplit_kernel<<<cdiv(HDIM * HDIM, 256), 256, 0, stream>>>(W_dp + WOFF, WTdp_hi + WOFF, WTdp_lo + WOFF, HDIM, HDIM);
    wsplit_kernel<<<cdiv(HDIM * HDIM, 256), 256, 0, stream>>>(W_cp + WOFF, WTcp_hi + WOFF, WTcp_lo + WOFF, HDIM, HDIM);
  }

  GatBufs gb{als, ald, out32, Hb};

  for (int l = 0; l < L; ++l) {
    const int VOFF = l * HDIM;
    const int WOFF = l * HDIM * HDIM;
    run_gat(stream, xp_hi, xp_lo, NP, nullptr, nullptr, NP, /*same=*/true,
            WTpp_hi + WOFF, WTpp_lo + WOFF, as_pp + VOFF, ad_pp + VOFF, b_pp + VOFF,
            sd_pp, rp_pp, gb, xp_hi, xp_lo, 0);
    run_gat(stream, xp_hi, xp_lo, NP, xd_hi, xd_lo, ND, false,
            WTdp_hi + WOFF, WTdp_lo + WOFF, as_dp + VOFF, ad_dp + VOFF, b_dp + VOFF,
            sd_dp, rp_dp, gb, xd_hi, xd_lo, 1);
    run_gat(stream, xp_hi, xp_lo, NP, xc_hi, xc_lo, NC, false,
            WTcp_hi + WOFF, WTcp_lo + WOFF, as_cp + VOFF, ad_cp + VOFF, b_cp + VOFF,
            sd_cp, rp_cp, gb, xc_hi, xc_lo, 1);
  }

  // ---------------- head
  l2norm_sp_kernel<<<cdiv(ND, 4), 256, 0, stream>>>(xd_hi, xd_lo, xdn_hi, xdn_lo, ND);
  l2norm_sp_kernel<<<cdiv(NC, 4), 256, 0, stream>>>(xc_hi, xc_lo, xcn_hi, xcn_lo, NC);

  wsplit_kernel<<<cdiv(768 * 1536, 256), 256, 0, stream>>>(W1, W1T_hi, W1T_lo, 768, 1536);
  wsplit_kernel<<<cdiv(1536 * 512, 256), 256, 0, stream>>>(W2, W2T_hi, W2T_lo, 1536, 512);

  float* outp = (float*)d_out;
  out_init_kernel<<<cdiv(B * 2, 256), 256, 0, stream>>>(outp, b3, B * 2);

  for (int c0 = 0; c0 < B; c0 += CH) {
    int M = (B - c0) < CH ? (B - c0) : CH;
    // MLP1: gathered A, packed-uint h1 out, relu
    gemm_dn<2, 1, 1, 0><<<gemm_grid(M, 1536), 256, 0, stream>>>(
        nullptr, nullptr, xdn_hi, xdn_lo, xcn_hi, xcn_lo, drug1, drug2, cellb, c0,
        W1T_hi, W1T_lo, b1, nullptr, nullptr, nullptr, nullptr,
        nullptr, nullptr, h1p, M, 1536, 768);
    // MLP2 + fused W3 head: packed A, relu, atomic logits into d_out
    gemm_dn<3, 5, 1, 0><<<gemm_grid(M, 512), 256, 0, stream>>>(
        (const ushort*)h1p, nullptr, nullptr, nullptr, nullptr, nullptr, nullptr, nullptr, nullptr, 0,
        W2T_hi, W2T_lo, b2, W3, nullptr, nullptr, nullptr,
        outp + (size_t)c0 * 2, nullptr, nullptr, M, 512, 1536);
  }
}